// Round 11
// baseline (222.319 us; speedup 1.0000x reference)
//
#include <hip/hip_runtime.h>

#define N_NODES 50000
#define N_EDGES 800000
#define D 128
#define NB 196            // partition chunk blocks
#define CHUNK 4096        // edges per chunk (196*4096 = 802816 >= 800000)
#define NBKT 391          // buckets = dst>>7 (128 nodes each)
#define LHM (NBKT * NB)   // hist matrix length 76636
#define NSB ((LHM + 255) / 256)   // 300
#define GB ((N_NODES + 127) / 128)   // 391 gemm tiles

typedef unsigned int uint32;
typedef unsigned short ushort;
typedef __attribute__((ext_vector_type(8))) short s8v;   // 8 x bf16 bits
typedef __attribute__((ext_vector_type(4))) float f4v;   // MFMA accumulator

__device__ __forceinline__ ushort f2bf(float f) {   // RNE bf16
    unsigned u = __float_as_uint(f);
    u += 0x7FFFu + ((u >> 16) & 1u);
    return (ushort)(u >> 16);
}
__device__ __forceinline__ float bf_lo(uint32 u) { return __uint_as_float(u << 16); }
__device__ __forceinline__ float bf_hi(uint32 u) { return __uint_as_float(u & 0xFFFF0000u); }

// ---- block-wide inclusive scan helper (256 threads = 4 waves) ----
__device__ __forceinline__ int block_incl_scan(int v, int t) {
    int lane = t & 63, wv = t >> 6;
    int incl = v;
    #pragma unroll
    for (int off = 1; off < 64; off <<= 1) {
        int u = __shfl_up(incl, off, 64);
        if (lane >= off) incl += u;
    }
    __shared__ int wsums[4];
    if (lane == 63) wsums[wv] = incl;
    __syncthreads();
    int add = 0;
    if (wv > 0) add += wsums[0];
    if (wv > 1) add += wsums[1];
    if (wv > 2) add += wsums[2];
    return incl + add;
}

// ---- K1: per-chunk bucket histogram (private slots, NO global atomics) + wprep ----
__global__ __launch_bounds__(256) void phaseA_kernel(const int* __restrict__ dst,
                                                     int* __restrict__ histM,
                                                     const float* __restrict__ W1,
                                                     const float* __restrict__ W2,
                                                     ushort* __restrict__ W1t,
                                                     ushort* __restrict__ W2t) {
    int t = threadIdx.x, blk = blockIdx.x;
    if (blk >= NB) {                      // 2 tail blocks: weight transpose+cvt
        const float* W = (blk - NB) ? W2 : W1;
        ushort* Wt = (blk - NB) ? W2t : W1t;
        #pragma unroll
        for (int it = 0; it < 16; it++) {
            int fid = t + it * 256;       // float4 id 0..4095
            int k = fid >> 5;
            int n0 = (fid & 31) * 4;
            float4 w = ((const float4*)W)[fid];
            Wt[(n0 + 0) * D + k] = f2bf(w.x);
            Wt[(n0 + 1) * D + k] = f2bf(w.y);
            Wt[(n0 + 2) * D + k] = f2bf(w.z);
            Wt[(n0 + 3) * D + k] = f2bf(w.w);
        }
        return;
    }
    __shared__ int lc[NBKT];
    for (int i = t; i < NBKT; i += 256) lc[i] = 0;
    __syncthreads();
    int e0 = blk * CHUNK;
    #pragma unroll
    for (int j = 0; j < 16; j++) {
        int e = e0 + t + j * 256;
        if (e < N_EDGES) atomicAdd(&lc[dst[e] >> 7], 1);
    }
    __syncthreads();
    for (int i = t; i < NBKT; i += 256)
        histM[i * NB + blk] = lc[i];      // bucket-major, block-minor (private slot)
}

// ---- scan pass 1: block-local exclusive + block sums ----
__global__ __launch_bounds__(256) void scan1g(const int* __restrict__ in,
                                              int* __restrict__ out,
                                              int* __restrict__ bsum) {
    int t = threadIdx.x, blk = blockIdx.x;
    int i = blk * 256 + t;
    int v = (i < LHM) ? in[i] : 0;
    int incl = block_incl_scan(v, t);
    if (i < LHM) out[i] = incl - v;
    if (t == 255) bsum[blk] = incl;
}

// ---- scan pass 2 (merged): each block reduces its bsum-prefix, adds to its tile ----
__global__ __launch_bounds__(256) void scan23g(int* __restrict__ out,
                                               const int* __restrict__ bsum) {
    int t = threadIdx.x, blk = blockIdx.x;
    int local = 0;
    for (int i = t; i < blk; i += 256) local += bsum[i];
    int lane = t & 63, wv = t >> 6;
    #pragma unroll
    for (int off = 32; off > 0; off >>= 1) local += __shfl_down(local, off, 64);
    __shared__ int ws[4];
    if (lane == 0) ws[wv] = local;
    __syncthreads();
    int boff = ws[0] + ws[1] + ws[2] + ws[3];
    int i = blk * 256 + t;
    if (i < LHM) out[i] += boff;
}

// ---- K3: phaseC — partition edges into bucket-major order (no global atomics) ----
__global__ __launch_bounds__(256) void phaseC_kernel(const int* __restrict__ src,
                                                     const int* __restrict__ dst,
                                                     const int* __restrict__ base,
                                                     uint32* __restrict__ edgeTmp) {
    __shared__ int cur[NBKT];
    int t = threadIdx.x, blk = blockIdx.x;
    for (int i = t; i < NBKT; i += 256) cur[i] = base[i * NB + blk];
    __syncthreads();
    int e0 = blk * CHUNK;
    for (int i = t; i < CHUNK; i += 256) {
        int e = e0 + i;
        if (e < N_EDGES) {
            uint32 s = (uint32)src[e], d = (uint32)dst[e];
            int p = atomicAdd(&cur[d >> 7], 1);      // LDS atomic
            edgeTmp[p] = (s << 16) | d;              // both < 65536
        }
    }
}

// ---- K4: per-bucket (128 nodes) counting sort + rowstart + dis ----
__global__ __launch_bounds__(256) void phaseD_kernel(const uint32* __restrict__ edgeTmp,
                                                     const int* __restrict__ base,
                                                     int* __restrict__ rowstart,
                                                     float* __restrict__ dis,
                                                     ushort* __restrict__ e16) {
    __shared__ int cnt[128];
    __shared__ int cur[128];
    int t = threadIdx.x, b = blockIdx.x;
    int beg = base[b * NB];
    int end = (b == NBKT - 1) ? N_EDGES : base[(b + 1) * NB];
    if (t < 128) cnt[t] = 0;
    __syncthreads();
    for (int p = beg + t; p < end; p += 256)
        atomicAdd(&cnt[edgeTmp[p] & 127], 1);
    __syncthreads();
    int c = (t < 128) ? cnt[t] : 0;
    int incl = block_incl_scan(c, t);
    int excl = incl - c;
    int node = b * 128 + t;
    if (t < 128) {
        if (node <= N_NODES) rowstart[node] = beg + excl;
        if (node < N_NODES) dis[node] = rsqrtf((float)(c + 1));
        cur[t] = excl;
    }
    __syncthreads();
    for (int p = beg + t; p < end; p += 256) {
        uint32 u = edgeTmp[p];
        int r = atomicAdd(&cur[u & 127], 1);            // LDS atomic
        e16[beg + r] = (ushort)(u >> 16);
    }
}

// ---- Hb = bf16(dis[r] * (X @ W)) via MFMA 16x16x32 bf16, dis folded ----
template<bool BF16IN>
__global__ __launch_bounds__(256) void gemm_mfma(const void* __restrict__ Xv,
                                                 const ushort* __restrict__ Wt,
                                                 const float* __restrict__ dis,
                                                 ushort* __restrict__ Hb) {
    __shared__ ushort Cs[128 * 136];
    int t = threadIdx.x;
    int wv = t >> 6, lane = t & 63;
    int q = lane >> 4, m = lane & 15;
    int rbase = blockIdx.x * 128 + wv * 32;
    f4v zero = {0.f, 0.f, 0.f, 0.f};
    f4v acc[2][8];
    #pragma unroll
    for (int mt = 0; mt < 2; mt++)
        #pragma unroll
        for (int n = 0; n < 8; n++) acc[mt][n] = zero;

    #pragma unroll
    for (int kt = 0; kt < 4; kt++) {
        int k0 = kt * 32 + q * 8;
        s8v a[2];
        #pragma unroll
        for (int mt = 0; mt < 2; mt++) {
            int row = rbase + mt * 16 + m;
            if (row >= N_NODES) row = N_NODES - 1;
            if (BF16IN) {
                const ushort* xp = (const ushort*)Xv + (size_t)row * D + k0;
                a[mt] = *(const s8v*)xp;                       // 16B load
            } else {
                const float* xp = (const float*)Xv + (size_t)row * D + k0;
                float4 u0 = *(const float4*)xp;
                float4 u1 = *(const float4*)(xp + 4);
                s8v av;
                av[0] = (short)f2bf(u0.x); av[1] = (short)f2bf(u0.y);
                av[2] = (short)f2bf(u0.z); av[3] = (short)f2bf(u0.w);
                av[4] = (short)f2bf(u1.x); av[5] = (short)f2bf(u1.y);
                av[6] = (short)f2bf(u1.z); av[7] = (short)f2bf(u1.w);
                a[mt] = av;
            }
        }
        #pragma unroll
        for (int n = 0; n < 8; n++) {
            s8v b = *(const s8v*)(Wt + (size_t)(n * 16 + m) * D + k0);
            acc[0][n] = __builtin_amdgcn_mfma_f32_16x16x32_bf16(a[0], b, acc[0][n], 0, 0, 0);
            acc[1][n] = __builtin_amdgcn_mfma_f32_16x16x32_bf16(a[1], b, acc[1][n], 0, 0, 0);
        }
    }
    float disv[2][4];
    #pragma unroll
    for (int mt = 0; mt < 2; mt++)
        #pragma unroll
        for (int r = 0; r < 4; r++) {
            int row = rbase + mt * 16 + q * 4 + r;
            if (row >= N_NODES) row = N_NODES - 1;
            disv[mt][r] = dis[row];
        }
    #pragma unroll
    for (int mt = 0; mt < 2; mt++)
        #pragma unroll
        for (int n = 0; n < 8; n++)
            #pragma unroll
            for (int r = 0; r < 4; r++) {
                int row = wv * 32 + mt * 16 + q * 4 + r;
                Cs[row * 136 + n * 16 + m] = f2bf(acc[mt][n][r] * disv[mt][r]);
            }
    __syncthreads();
    int gbase = blockIdx.x * 128;
    #pragma unroll
    for (int it = 0; it < 8; it++) {
        int cid = t + it * 256;
        int row = cid >> 4, off = (cid & 15) * 8;
        int grow = gbase + row;
        if (grow < N_NODES) {
            s8v v = *(const s8v*)(Cs + row * 136 + off);
            *(s8v*)(Hb + (size_t)grow * D + off) = v;
        }
    }
}

// ---- aggregate: out = relu(dis[n]*(Hb[n]+sum Hb[src])+b), 16 lanes/node ----
// e16 indices loaded as uint4 (8 ushorts, 1 VMEM) after peeling to 16B alignment.
__device__ __forceinline__ void acc8(float* a, uint4 v) {
    a[0] += bf_lo(v.x); a[1] += bf_hi(v.x);
    a[2] += bf_lo(v.y); a[3] += bf_hi(v.y);
    a[4] += bf_lo(v.z); a[5] += bf_hi(v.z);
    a[6] += bf_lo(v.w); a[7] += bf_hi(v.w);
}

template<bool BF16OUT>
__global__ __launch_bounds__(256) void aggr_kernel(const uint4* __restrict__ Hb4,
                                                   const float* __restrict__ dis,
                                                   const int* __restrict__ rowstart,
                                                   const ushort* __restrict__ e16,
                                                   const float* __restrict__ bias,
                                                   void* __restrict__ Hout) {
    int t = threadIdx.x;
    int li = t & 15;                       // lane in group: channels li*8..li*8+7
    int n = blockIdx.x * 16 + (t >> 4);    // 50000 = 3125*16
    float dn = dis[n];
    float a[8];
    {
        uint4 sv = Hb4[(size_t)n * 16 + li];   // self term (dis[n] folded into Hb)
        a[0] = bf_lo(sv.x); a[1] = bf_hi(sv.x);
        a[2] = bf_lo(sv.y); a[3] = bf_hi(sv.y);
        a[4] = bf_lo(sv.z); a[5] = bf_hi(sv.z);
        a[6] = bf_lo(sv.w); a[7] = bf_hi(sv.w);
    }
    int beg = rowstart[n], end = rowstart[n + 1];
    int p = beg;
    int a0 = (beg + 7) & ~7;               // first 16B-aligned ushort index
    if (a0 > end) a0 = end;
    for (; p < a0; p++) {                  // peel head to alignment
        uint4 v0 = Hb4[(size_t)e16[p] * 16 + li];
        acc8(a, v0);
    }
    for (; p + 7 < end; p += 8) {          // 1 uint4 index load + 8 gathers
        uint4 er = *(const uint4*)(e16 + p);
        int s0 = er.x & 0xFFFF, s1 = er.x >> 16;
        int s2 = er.y & 0xFFFF, s3 = er.y >> 16;
        int s4 = er.z & 0xFFFF, s5 = er.z >> 16;
        int s6 = er.w & 0xFFFF, s7 = er.w >> 16;
        uint4 v0 = Hb4[(size_t)s0 * 16 + li];
        uint4 v1 = Hb4[(size_t)s1 * 16 + li];
        uint4 v2 = Hb4[(size_t)s2 * 16 + li];
        uint4 v3 = Hb4[(size_t)s3 * 16 + li];
        uint4 v4 = Hb4[(size_t)s4 * 16 + li];
        uint4 v5 = Hb4[(size_t)s5 * 16 + li];
        uint4 v6 = Hb4[(size_t)s6 * 16 + li];
        uint4 v7 = Hb4[(size_t)s7 * 16 + li];
        acc8(a, v0); acc8(a, v1); acc8(a, v2); acc8(a, v3);
        acc8(a, v4); acc8(a, v5); acc8(a, v6); acc8(a, v7);
    }
    for (; p < end; p++) {                 // tail
        uint4 v0 = Hb4[(size_t)e16[p] * 16 + li];
        acc8(a, v0);
    }
    const float4* b4 = (const float4*)bias;
    float4 bb0 = b4[li * 2], bb1 = b4[li * 2 + 1];
    float r0 = fmaxf(fmaf(dn, a[0], bb0.x), 0.f);
    float r1 = fmaxf(fmaf(dn, a[1], bb0.y), 0.f);
    float r2 = fmaxf(fmaf(dn, a[2], bb0.z), 0.f);
    float r3 = fmaxf(fmaf(dn, a[3], bb0.w), 0.f);
    float r4 = fmaxf(fmaf(dn, a[4], bb1.x), 0.f);
    float r5 = fmaxf(fmaf(dn, a[5], bb1.y), 0.f);
    float r6 = fmaxf(fmaf(dn, a[6], bb1.z), 0.f);
    float r7 = fmaxf(fmaf(dn, a[7], bb1.w), 0.f);
    if (BF16OUT) {
        uint4 o;
        o.x = (uint32)f2bf(r0) | ((uint32)f2bf(r1) << 16);
        o.y = (uint32)f2bf(r2) | ((uint32)f2bf(r3) << 16);
        o.z = (uint32)f2bf(r4) | ((uint32)f2bf(r5) << 16);
        o.w = (uint32)f2bf(r6) | ((uint32)f2bf(r7) << 16);
        ((uint4*)Hout)[(size_t)n * 16 + li] = o;
    } else {
        float4* H4 = (float4*)Hout;
        float4 o0; o0.x = r0; o0.y = r1; o0.z = r2; o0.w = r3;
        float4 o1; o1.x = r4; o1.y = r5; o1.z = r6; o1.w = r7;
        H4[(size_t)n * 32 + li * 2]     = o0;
        H4[(size_t)n * 32 + li * 2 + 1] = o1;
    }
}

extern "C" void kernel_launch(void* const* d_in, const int* in_sizes, int n_in,
                              void* d_out, int out_size, void* d_ws, size_t ws_size,
                              hipStream_t stream) {
    const float* x  = (const float*)d_in[0];
    const int*   ei = (const int*)d_in[1];   // int32 per harness contract
    const float* W1 = (const float*)d_in[2];
    const float* b1 = (const float*)d_in[3];
    const float* W2 = (const float*)d_in[4];
    const float* b2 = (const float*)d_in[5];
    float* out = (float*)d_out;

    char* ws = (char*)d_ws;
    size_t off = 0;
    auto alloc = [&](size_t bytes) -> void* {
        void* p = ws + off;
        off += (bytes + 255) & ~(size_t)255;
        return p;
    };
    int*    histM    = (int*)alloc((size_t)LHM * 4);
    int*    base     = (int*)alloc((size_t)LHM * 4);
    int*    bsum     = (int*)alloc((size_t)NSB * 4);
    int*    rowstart = (int*)alloc((size_t)(N_NODES + 1) * 4);
    float*  dis      = (float*)alloc((size_t)N_NODES * 4);
    uint32* edgeTmp  = (uint32*)alloc((size_t)N_EDGES * 4);
    ushort* e16      = (ushort*)alloc((size_t)(N_EDGES + 8) * 2);
    ushort* Hb       = (ushort*)alloc((size_t)N_NODES * D * 2);
    ushort* HO1      = (ushort*)alloc((size_t)N_NODES * D * 2);   // layer-1 out bf16
    ushort* W1t      = (ushort*)alloc((size_t)D * D * 2);
    ushort* W2t      = (ushort*)alloc((size_t)D * D * 2);

    const int* src = ei;             // edge_index[0]
    const int* dst = ei + N_EDGES;   // edge_index[1]

    phaseA_kernel<<<NB + 2, 256, 0, stream>>>(dst, histM, W1, W2, W1t, W2t);
    scan1g<<<NSB, 256, 0, stream>>>(histM, base, bsum);
    scan23g<<<NSB, 256, 0, stream>>>(base, bsum);
    phaseC_kernel<<<NB, 256, 0, stream>>>(src, dst, base, edgeTmp);
    phaseD_kernel<<<NBKT, 256, 0, stream>>>(edgeTmp, base, rowstart, dis, e16);

    gemm_mfma<false><<<GB, 256, 0, stream>>>(x, W1t, dis, Hb);
    aggr_kernel<true><<<N_NODES / 16, 256, 0, stream>>>((const uint4*)Hb, dis, rowstart,
                                                        e16, b1, HO1);
    gemm_mfma<true><<<GB, 256, 0, stream>>>(HO1, W2t, dis, Hb);
    aggr_kernel<false><<<N_NODES / 16, 256, 0, stream>>>((const uint4*)Hb, dis, rowstart,
                                                         e16, b2, out);
}

// Round 12
// 222.030 us; speedup vs baseline: 1.0013x; 1.0013x over previous
//
#include <hip/hip_runtime.h>

#define N_NODES 50000
#define N_EDGES 800000
#define D 128
#define NB 392            // partition chunk blocks (full CU coverage)
#define CHUNK 2048        // edges per chunk (392*2048 = 802816 >= 800000)
#define NBKT 391          // buckets = dst>>7 (128 nodes each)
#define LHM (NBKT * NB)   // hist matrix length 153272
#define NSB ((LHM + 255) / 256)   // 599
#define GB ((N_NODES + 127) / 128)   // 391 gemm tiles

typedef unsigned int uint32;
typedef unsigned short ushort;
typedef __attribute__((ext_vector_type(8))) short s8v;   // 8 x bf16 bits
typedef __attribute__((ext_vector_type(4))) float f4v;   // MFMA accumulator

__device__ __forceinline__ ushort f2bf(float f) {   // RNE bf16
    unsigned u = __float_as_uint(f);
    u += 0x7FFFu + ((u >> 16) & 1u);
    return (ushort)(u >> 16);
}
__device__ __forceinline__ float bf_lo(uint32 u) { return __uint_as_float(u << 16); }
__device__ __forceinline__ float bf_hi(uint32 u) { return __uint_as_float(u & 0xFFFF0000u); }

// ---- block-wide inclusive scan helper (256 threads = 4 waves) ----
__device__ __forceinline__ int block_incl_scan(int v, int t) {
    int lane = t & 63, wv = t >> 6;
    int incl = v;
    #pragma unroll
    for (int off = 1; off < 64; off <<= 1) {
        int u = __shfl_up(incl, off, 64);
        if (lane >= off) incl += u;
    }
    __shared__ int wsums[4];
    if (lane == 63) wsums[wv] = incl;
    __syncthreads();
    int add = 0;
    if (wv > 0) add += wsums[0];
    if (wv > 1) add += wsums[1];
    if (wv > 2) add += wsums[2];
    return incl + add;
}

// ---- K1: per-chunk bucket histogram (private slots, NO global atomics) + wprep ----
__global__ __launch_bounds__(256) void phaseA_kernel(const int* __restrict__ dst,
                                                     int* __restrict__ histM,
                                                     const float* __restrict__ W1,
                                                     const float* __restrict__ W2,
                                                     ushort* __restrict__ W1t,
                                                     ushort* __restrict__ W2t) {
    int t = threadIdx.x, blk = blockIdx.x;
    if (blk >= NB) {                      // 2 tail blocks: weight transpose+cvt
        const float* W = (blk - NB) ? W2 : W1;
        ushort* Wt = (blk - NB) ? W2t : W1t;
        #pragma unroll
        for (int it = 0; it < 16; it++) {
            int fid = t + it * 256;       // float4 id 0..4095
            int k = fid >> 5;
            int n0 = (fid & 31) * 4;
            float4 w = ((const float4*)W)[fid];
            Wt[(n0 + 0) * D + k] = f2bf(w.x);
            Wt[(n0 + 1) * D + k] = f2bf(w.y);
            Wt[(n0 + 2) * D + k] = f2bf(w.z);
            Wt[(n0 + 3) * D + k] = f2bf(w.w);
        }
        return;
    }
    __shared__ int lc[NBKT];
    for (int i = t; i < NBKT; i += 256) lc[i] = 0;
    __syncthreads();
    int e0 = blk * CHUNK;
    #pragma unroll
    for (int j = 0; j < 8; j++) {
        int e = e0 + t + j * 256;
        if (e < N_EDGES) atomicAdd(&lc[dst[e] >> 7], 1);
    }
    __syncthreads();
    for (int i = t; i < NBKT; i += 256)
        histM[i * NB + blk] = lc[i];      // bucket-major, block-minor (private slot)
}

// ---- scan pass 1: block-local exclusive + block sums ----
__global__ __launch_bounds__(256) void scan1g(const int* __restrict__ in,
                                              int* __restrict__ out,
                                              int* __restrict__ bsum) {
    int t = threadIdx.x, blk = blockIdx.x;
    int i = blk * 256 + t;
    int v = (i < LHM) ? in[i] : 0;
    int incl = block_incl_scan(v, t);
    if (i < LHM) out[i] = incl - v;
    if (t == 255) bsum[blk] = incl;
}

// ---- scan pass 2 (merged): each block reduces its bsum-prefix, adds to its tile ----
__global__ __launch_bounds__(256) void scan23g(int* __restrict__ out,
                                               const int* __restrict__ bsum) {
    int t = threadIdx.x, blk = blockIdx.x;
    int local = 0;
    for (int i = t; i < blk; i += 256) local += bsum[i];
    int lane = t & 63, wv = t >> 6;
    #pragma unroll
    for (int off = 32; off > 0; off >>= 1) local += __shfl_down(local, off, 64);
    __shared__ int ws[4];
    if (lane == 0) ws[wv] = local;
    __syncthreads();
    int boff = ws[0] + ws[1] + ws[2] + ws[3];
    int i = blk * 256 + t;
    if (i < LHM) out[i] += boff;
}

// ---- K3: phaseC — partition edges into bucket-major order (no global atomics) ----
__global__ __launch_bounds__(256) void phaseC_kernel(const int* __restrict__ src,
                                                     const int* __restrict__ dst,
                                                     const int* __restrict__ base,
                                                     uint32* __restrict__ edgeTmp) {
    __shared__ int cur[NBKT];
    int t = threadIdx.x, blk = blockIdx.x;
    for (int i = t; i < NBKT; i += 256) cur[i] = base[i * NB + blk];
    __syncthreads();
    int e0 = blk * CHUNK;
    #pragma unroll
    for (int j = 0; j < 8; j++) {
        int e = e0 + t + j * 256;
        if (e < N_EDGES) {
            uint32 s = (uint32)src[e], d = (uint32)dst[e];
            int p = atomicAdd(&cur[d >> 7], 1);      // LDS atomic
            edgeTmp[p] = (s << 16) | d;              // both < 65536
        }
    }
}

// ---- K4: per-bucket (128 nodes) counting sort + rowstart + dis ----
__global__ __launch_bounds__(256) void phaseD_kernel(const uint32* __restrict__ edgeTmp,
                                                     const int* __restrict__ base,
                                                     int* __restrict__ rowstart,
                                                     float* __restrict__ dis,
                                                     ushort* __restrict__ e16) {
    __shared__ int cnt[128];
    __shared__ int cur[128];
    int t = threadIdx.x, b = blockIdx.x;
    int beg = base[b * NB];
    int end = (b == NBKT - 1) ? N_EDGES : base[(b + 1) * NB];
    if (t < 128) cnt[t] = 0;
    __syncthreads();
    for (int p = beg + t; p < end; p += 256)
        atomicAdd(&cnt[edgeTmp[p] & 127], 1);
    __syncthreads();
    int c = (t < 128) ? cnt[t] : 0;
    int incl = block_incl_scan(c, t);
    int excl = incl - c;
    int node = b * 128 + t;
    if (t < 128) {
        if (node <= N_NODES) rowstart[node] = beg + excl;
        if (node < N_NODES) dis[node] = rsqrtf((float)(c + 1));
        cur[t] = excl;
    }
    __syncthreads();
    for (int p = beg + t; p < end; p += 256) {
        uint32 u = edgeTmp[p];
        int r = atomicAdd(&cur[u & 127], 1);            // LDS atomic
        e16[beg + r] = (ushort)(u >> 16);
    }
}

// ---- Hb = bf16(dis[r] * (X @ W)) via MFMA 16x16x32 bf16, dis folded ----
template<bool BF16IN>
__global__ __launch_bounds__(256) void gemm_mfma(const void* __restrict__ Xv,
                                                 const ushort* __restrict__ Wt,
                                                 const float* __restrict__ dis,
                                                 ushort* __restrict__ Hb) {
    __shared__ ushort Cs[128 * 136];
    int t = threadIdx.x;
    int wv = t >> 6, lane = t & 63;
    int q = lane >> 4, m = lane & 15;
    int rbase = blockIdx.x * 128 + wv * 32;
    f4v zero = {0.f, 0.f, 0.f, 0.f};
    f4v acc[2][8];
    #pragma unroll
    for (int mt = 0; mt < 2; mt++)
        #pragma unroll
        for (int n = 0; n < 8; n++) acc[mt][n] = zero;

    #pragma unroll
    for (int kt = 0; kt < 4; kt++) {
        int k0 = kt * 32 + q * 8;
        s8v a[2];
        #pragma unroll
        for (int mt = 0; mt < 2; mt++) {
            int row = rbase + mt * 16 + m;
            if (row >= N_NODES) row = N_NODES - 1;
            if (BF16IN) {
                const ushort* xp = (const ushort*)Xv + (size_t)row * D + k0;
                a[mt] = *(const s8v*)xp;                       // 16B load
            } else {
                const float* xp = (const float*)Xv + (size_t)row * D + k0;
                float4 u0 = *(const float4*)xp;
                float4 u1 = *(const float4*)(xp + 4);
                s8v av;
                av[0] = (short)f2bf(u0.x); av[1] = (short)f2bf(u0.y);
                av[2] = (short)f2bf(u0.z); av[3] = (short)f2bf(u0.w);
                av[4] = (short)f2bf(u1.x); av[5] = (short)f2bf(u1.y);
                av[6] = (short)f2bf(u1.z); av[7] = (short)f2bf(u1.w);
                a[mt] = av;
            }
        }
        #pragma unroll
        for (int n = 0; n < 8; n++) {
            s8v b = *(const s8v*)(Wt + (size_t)(n * 16 + m) * D + k0);
            acc[0][n] = __builtin_amdgcn_mfma_f32_16x16x32_bf16(a[0], b, acc[0][n], 0, 0, 0);
            acc[1][n] = __builtin_amdgcn_mfma_f32_16x16x32_bf16(a[1], b, acc[1][n], 0, 0, 0);
        }
    }
    float disv[2][4];
    #pragma unroll
    for (int mt = 0; mt < 2; mt++)
        #pragma unroll
        for (int r = 0; r < 4; r++) {
            int row = rbase + mt * 16 + q * 4 + r;
            if (row >= N_NODES) row = N_NODES - 1;
            disv[mt][r] = dis[row];
        }
    #pragma unroll
    for (int mt = 0; mt < 2; mt++)
        #pragma unroll
        for (int n = 0; n < 8; n++)
            #pragma unroll
            for (int r = 0; r < 4; r++) {
                int row = wv * 32 + mt * 16 + q * 4 + r;
                Cs[row * 136 + n * 16 + m] = f2bf(acc[mt][n][r] * disv[mt][r]);
            }
    __syncthreads();
    int gbase = blockIdx.x * 128;
    #pragma unroll
    for (int it = 0; it < 8; it++) {
        int cid = t + it * 256;
        int row = cid >> 4, off = (cid & 15) * 8;
        int grow = gbase + row;
        if (grow < N_NODES) {
            s8v v = *(const s8v*)(Cs + row * 136 + off);
            *(s8v*)(Hb + (size_t)grow * D + off) = v;
        }
    }
}

// ---- aggregate: out = relu(dis[n]*(Hb[n]+sum Hb[src])+b), 16 lanes/node ----
__device__ __forceinline__ void acc8(float* a, uint4 v) {
    a[0] += bf_lo(v.x); a[1] += bf_hi(v.x);
    a[2] += bf_lo(v.y); a[3] += bf_hi(v.y);
    a[4] += bf_lo(v.z); a[5] += bf_hi(v.z);
    a[6] += bf_lo(v.w); a[7] += bf_hi(v.w);
}

template<bool BF16OUT>
__global__ __launch_bounds__(256) void aggr_kernel(const uint4* __restrict__ Hb4,
                                                   const float* __restrict__ dis,
                                                   const int* __restrict__ rowstart,
                                                   const ushort* __restrict__ e16,
                                                   const float* __restrict__ bias,
                                                   void* __restrict__ Hout) {
    int t = threadIdx.x;
    int li = t & 15;                       // lane in group: channels li*8..li*8+7
    int n = blockIdx.x * 16 + (t >> 4);    // 50000 = 3125*16
    float dn = dis[n];
    float a[8];
    {
        uint4 sv = Hb4[(size_t)n * 16 + li];   // self term (dis[n] folded into Hb)
        a[0] = bf_lo(sv.x); a[1] = bf_hi(sv.x);
        a[2] = bf_lo(sv.y); a[3] = bf_hi(sv.y);
        a[4] = bf_lo(sv.z); a[5] = bf_hi(sv.z);
        a[6] = bf_lo(sv.w); a[7] = bf_hi(sv.w);
    }
    int beg = rowstart[n], end = rowstart[n + 1];
    int p = beg;
    int a0 = (beg + 7) & ~7;               // first 16B-aligned ushort index
    if (a0 > end) a0 = end;
    for (; p < a0; p++) {                  // peel head to alignment
        uint4 v0 = Hb4[(size_t)e16[p] * 16 + li];
        acc8(a, v0);
    }
    for (; p + 7 < end; p += 8) {          // 1 uint4 index load + 8 gathers
        uint4 er = *(const uint4*)(e16 + p);
        int s0 = er.x & 0xFFFF, s1 = er.x >> 16;
        int s2 = er.y & 0xFFFF, s3 = er.y >> 16;
        int s4 = er.z & 0xFFFF, s5 = er.z >> 16;
        int s6 = er.w & 0xFFFF, s7 = er.w >> 16;
        uint4 v0 = Hb4[(size_t)s0 * 16 + li];
        uint4 v1 = Hb4[(size_t)s1 * 16 + li];
        uint4 v2 = Hb4[(size_t)s2 * 16 + li];
        uint4 v3 = Hb4[(size_t)s3 * 16 + li];
        uint4 v4 = Hb4[(size_t)s4 * 16 + li];
        uint4 v5 = Hb4[(size_t)s5 * 16 + li];
        uint4 v6 = Hb4[(size_t)s6 * 16 + li];
        uint4 v7 = Hb4[(size_t)s7 * 16 + li];
        acc8(a, v0); acc8(a, v1); acc8(a, v2); acc8(a, v3);
        acc8(a, v4); acc8(a, v5); acc8(a, v6); acc8(a, v7);
    }
    for (; p < end; p++) {                 // tail
        uint4 v0 = Hb4[(size_t)e16[p] * 16 + li];
        acc8(a, v0);
    }
    const float4* b4 = (const float4*)bias;
    float4 bb0 = b4[li * 2], bb1 = b4[li * 2 + 1];
    float r0 = fmaxf(fmaf(dn, a[0], bb0.x), 0.f);
    float r1 = fmaxf(fmaf(dn, a[1], bb0.y), 0.f);
    float r2 = fmaxf(fmaf(dn, a[2], bb0.z), 0.f);
    float r3 = fmaxf(fmaf(dn, a[3], bb0.w), 0.f);
    float r4 = fmaxf(fmaf(dn, a[4], bb1.x), 0.f);
    float r5 = fmaxf(fmaf(dn, a[5], bb1.y), 0.f);
    float r6 = fmaxf(fmaf(dn, a[6], bb1.z), 0.f);
    float r7 = fmaxf(fmaf(dn, a[7], bb1.w), 0.f);
    if (BF16OUT) {
        uint4 o;
        o.x = (uint32)f2bf(r0) | ((uint32)f2bf(r1) << 16);
        o.y = (uint32)f2bf(r2) | ((uint32)f2bf(r3) << 16);
        o.z = (uint32)f2bf(r4) | ((uint32)f2bf(r5) << 16);
        o.w = (uint32)f2bf(r6) | ((uint32)f2bf(r7) << 16);
        ((uint4*)Hout)[(size_t)n * 16 + li] = o;
    } else {
        float4* H4 = (float4*)Hout;
        float4 o0; o0.x = r0; o0.y = r1; o0.z = r2; o0.w = r3;
        float4 o1; o1.x = r4; o1.y = r5; o1.z = r6; o1.w = r7;
        H4[(size_t)n * 32 + li * 2]     = o0;
        H4[(size_t)n * 32 + li * 2 + 1] = o1;
    }
}

extern "C" void kernel_launch(void* const* d_in, const int* in_sizes, int n_in,
                              void* d_out, int out_size, void* d_ws, size_t ws_size,
                              hipStream_t stream) {
    const float* x  = (const float*)d_in[0];
    const int*   ei = (const int*)d_in[1];   // int32 per harness contract
    const float* W1 = (const float*)d_in[2];
    const float* b1 = (const float*)d_in[3];
    const float* W2 = (const float*)d_in[4];
    const float* b2 = (const float*)d_in[5];
    float* out = (float*)d_out;

    char* ws = (char*)d_ws;
    size_t off = 0;
    auto alloc = [&](size_t bytes) -> void* {
        void* p = ws + off;
        off += (bytes + 255) & ~(size_t)255;
        return p;
    };
    int*    histM    = (int*)alloc((size_t)LHM * 4);
    int*    base     = (int*)alloc((size_t)LHM * 4);
    int*    bsum     = (int*)alloc((size_t)NSB * 4);
    int*    rowstart = (int*)alloc((size_t)(N_NODES + 1) * 4);
    float*  dis      = (float*)alloc((size_t)N_NODES * 4);
    uint32* edgeTmp  = (uint32*)alloc((size_t)N_EDGES * 4);
    ushort* e16      = (ushort*)alloc((size_t)(N_EDGES + 8) * 2);
    ushort* Hb       = (ushort*)alloc((size_t)N_NODES * D * 2);
    ushort* HO1      = (ushort*)alloc((size_t)N_NODES * D * 2);   // layer-1 out bf16
    ushort* W1t      = (ushort*)alloc((size_t)D * D * 2);
    ushort* W2t      = (ushort*)alloc((size_t)D * D * 2);

    const int* src = ei;             // edge_index[0]
    const int* dst = ei + N_EDGES;   // edge_index[1]

    phaseA_kernel<<<NB + 2, 256, 0, stream>>>(dst, histM, W1, W2, W1t, W2t);
    scan1g<<<NSB, 256, 0, stream>>>(histM, base, bsum);
    scan23g<<<NSB, 256, 0, stream>>>(base, bsum);
    phaseC_kernel<<<NB, 256, 0, stream>>>(src, dst, base, edgeTmp);
    phaseD_kernel<<<NBKT, 256, 0, stream>>>(edgeTmp, base, rowstart, dis, e16);

    gemm_mfma<false><<<GB, 256, 0, stream>>>(x, W1t, dis, Hb);
    aggr_kernel<true><<<N_NODES / 16, 256, 0, stream>>>((const uint4*)Hb, dis, rowstart,
                                                        e16, b1, HO1);
    gemm_mfma<true><<<GB, 256, 0, stream>>>(HO1, W2t, dis, Hb);
    aggr_kernel<false><<<N_NODES / 16, 256, 0, stream>>>((const uint4*)Hb, dis, rowstart,
                                                         e16, b2, out);
}

// Round 13
// 207.528 us; speedup vs baseline: 1.0713x; 1.0699x over previous
//
#include <hip/hip_runtime.h>

#define N_NODES 50000
#define N_EDGES 800000
#define D 128
#define NB 392            // partition chunk blocks (full CU coverage)
#define CHUNK 2048        // edges per chunk (392*2048 = 802816 >= 800000)
#define NBKT 391          // buckets = dst>>7 (128 nodes each)
#define LHM (NBKT * NB)   // hist matrix length 153272
#define NSB ((LHM + 255) / 256)   // 599
#define GB ((N_NODES + 127) / 128)   // 391 gemm tiles

typedef unsigned int uint32;
typedef unsigned short ushort;
typedef __attribute__((ext_vector_type(8))) short s8v;   // 8 x bf16 bits
typedef __attribute__((ext_vector_type(4))) float f4v;   // MFMA accumulator

__device__ __forceinline__ ushort f2bf(float f) {   // RNE bf16
    unsigned u = __float_as_uint(f);
    u += 0x7FFFu + ((u >> 16) & 1u);
    return (ushort)(u >> 16);
}
__device__ __forceinline__ float bf_lo(uint32 u) { return __uint_as_float(u << 16); }
__device__ __forceinline__ float bf_hi(uint32 u) { return __uint_as_float(u & 0xFFFF0000u); }

// ---- block-wide inclusive scan helper (256 threads = 4 waves) ----
__device__ __forceinline__ int block_incl_scan(int v, int t) {
    int lane = t & 63, wv = t >> 6;
    int incl = v;
    #pragma unroll
    for (int off = 1; off < 64; off <<= 1) {
        int u = __shfl_up(incl, off, 64);
        if (lane >= off) incl += u;
    }
    __shared__ int wsums[4];
    if (lane == 63) wsums[wv] = incl;
    __syncthreads();
    int add = 0;
    if (wv > 0) add += wsums[0];
    if (wv > 1) add += wsums[1];
    if (wv > 2) add += wsums[2];
    return incl + add;
}

// ---- K1: per-chunk bucket histogram (private slots, NO global atomics) + wprep ----
__global__ __launch_bounds__(256) void phaseA_kernel(const int* __restrict__ dst,
                                                     int* __restrict__ histM,
                                                     const float* __restrict__ W1,
                                                     const float* __restrict__ W2,
                                                     ushort* __restrict__ W1t,
                                                     ushort* __restrict__ W2t) {
    int t = threadIdx.x, blk = blockIdx.x;
    if (blk >= NB) {                      // 2 tail blocks: weight transpose+cvt
        const float* W = (blk - NB) ? W2 : W1;
        ushort* Wt = (blk - NB) ? W2t : W1t;
        #pragma unroll
        for (int it = 0; it < 16; it++) {
            int fid = t + it * 256;       // float4 id 0..4095
            int k = fid >> 5;
            int n0 = (fid & 31) * 4;
            float4 w = ((const float4*)W)[fid];
            Wt[(n0 + 0) * D + k] = f2bf(w.x);
            Wt[(n0 + 1) * D + k] = f2bf(w.y);
            Wt[(n0 + 2) * D + k] = f2bf(w.z);
            Wt[(n0 + 3) * D + k] = f2bf(w.w);
        }
        return;
    }
    __shared__ int lc[NBKT];
    for (int i = t; i < NBKT; i += 256) lc[i] = 0;
    __syncthreads();
    int e0 = blk * CHUNK;
    #pragma unroll
    for (int j = 0; j < 8; j++) {
        int e = e0 + t + j * 256;
        if (e < N_EDGES) atomicAdd(&lc[dst[e] >> 7], 1);
    }
    __syncthreads();
    for (int i = t; i < NBKT; i += 256)
        histM[i * NB + blk] = lc[i];      // bucket-major, block-minor (private slot)
}

// ---- scan pass 1: block-local exclusive + block sums ----
__global__ __launch_bounds__(256) void scan1g(const int* __restrict__ in,
                                              int* __restrict__ out,
                                              int* __restrict__ bsum) {
    int t = threadIdx.x, blk = blockIdx.x;
    int i = blk * 256 + t;
    int v = (i < LHM) ? in[i] : 0;
    int incl = block_incl_scan(v, t);
    if (i < LHM) out[i] = incl - v;
    if (t == 255) bsum[blk] = incl;
}

// ---- scan pass 2 (merged): each block reduces its bsum-prefix, adds to its tile ----
__global__ __launch_bounds__(256) void scan23g(int* __restrict__ out,
                                               const int* __restrict__ bsum) {
    int t = threadIdx.x, blk = blockIdx.x;
    int local = 0;
    for (int i = t; i < blk; i += 256) local += bsum[i];
    int lane = t & 63, wv = t >> 6;
    #pragma unroll
    for (int off = 32; off > 0; off >>= 1) local += __shfl_down(local, off, 64);
    __shared__ int ws[4];
    if (lane == 0) ws[wv] = local;
    __syncthreads();
    int boff = ws[0] + ws[1] + ws[2] + ws[3];
    int i = blk * 256 + t;
    if (i < LHM) out[i] += boff;
}

// ---- K3: phaseC — partition edges into bucket-major order (no global atomics) ----
__global__ __launch_bounds__(256) void phaseC_kernel(const int* __restrict__ src,
                                                     const int* __restrict__ dst,
                                                     const int* __restrict__ base,
                                                     uint32* __restrict__ edgeTmp) {
    __shared__ int cur[NBKT];
    int t = threadIdx.x, blk = blockIdx.x;
    for (int i = t; i < NBKT; i += 256) cur[i] = base[i * NB + blk];
    __syncthreads();
    int e0 = blk * CHUNK;
    #pragma unroll
    for (int j = 0; j < 8; j++) {
        int e = e0 + t + j * 256;
        if (e < N_EDGES) {
            uint32 s = (uint32)src[e], d = (uint32)dst[e];
            int p = atomicAdd(&cur[d >> 7], 1);      // LDS atomic
            edgeTmp[p] = (s << 16) | d;              // both < 65536
        }
    }
}

// ---- K4: per-bucket (128 nodes) counting sort + rowstart + dis ----
__global__ __launch_bounds__(256) void phaseD_kernel(const uint32* __restrict__ edgeTmp,
                                                     const int* __restrict__ base,
                                                     int* __restrict__ rowstart,
                                                     float* __restrict__ dis,
                                                     ushort* __restrict__ e16) {
    __shared__ int cnt[128];
    __shared__ int cur[128];
    int t = threadIdx.x, b = blockIdx.x;
    int beg = base[b * NB];
    int end = (b == NBKT - 1) ? N_EDGES : base[(b + 1) * NB];
    if (t < 128) cnt[t] = 0;
    __syncthreads();
    for (int p = beg + t; p < end; p += 256)
        atomicAdd(&cnt[edgeTmp[p] & 127], 1);
    __syncthreads();
    int c = (t < 128) ? cnt[t] : 0;
    int incl = block_incl_scan(c, t);
    int excl = incl - c;
    int node = b * 128 + t;
    if (t < 128) {
        if (node <= N_NODES) rowstart[node] = beg + excl;
        if (node < N_NODES) dis[node] = rsqrtf((float)(c + 1));
        cur[t] = excl;
    }
    __syncthreads();
    for (int p = beg + t; p < end; p += 256) {
        uint32 u = edgeTmp[p];
        int r = atomicAdd(&cur[u & 127], 1);            // LDS atomic
        e16[beg + r] = (ushort)(u >> 16);
    }
}

// ---- Hb = bf16(dis[r] * (X @ W)) via MFMA 16x16x32 bf16, dis folded ----
template<bool BF16IN>
__global__ __launch_bounds__(256) void gemm_mfma(const void* __restrict__ Xv,
                                                 const ushort* __restrict__ Wt,
                                                 const float* __restrict__ dis,
                                                 ushort* __restrict__ Hb) {
    __shared__ ushort Cs[128 * 136];
    int t = threadIdx.x;
    int wv = t >> 6, lane = t & 63;
    int q = lane >> 4, m = lane & 15;
    int rbase = blockIdx.x * 128 + wv * 32;
    f4v zero = {0.f, 0.f, 0.f, 0.f};
    f4v acc[2][8];
    #pragma unroll
    for (int mt = 0; mt < 2; mt++)
        #pragma unroll
        for (int n = 0; n < 8; n++) acc[mt][n] = zero;

    #pragma unroll
    for (int kt = 0; kt < 4; kt++) {
        int k0 = kt * 32 + q * 8;
        s8v a[2];
        #pragma unroll
        for (int mt = 0; mt < 2; mt++) {
            int row = rbase + mt * 16 + m;
            if (row >= N_NODES) row = N_NODES - 1;
            if (BF16IN) {
                const ushort* xp = (const ushort*)Xv + (size_t)row * D + k0;
                a[mt] = *(const s8v*)xp;                       // 16B load
            } else {
                const float* xp = (const float*)Xv + (size_t)row * D + k0;
                float4 u0 = *(const float4*)xp;
                float4 u1 = *(const float4*)(xp + 4);
                s8v av;
                av[0] = (short)f2bf(u0.x); av[1] = (short)f2bf(u0.y);
                av[2] = (short)f2bf(u0.z); av[3] = (short)f2bf(u0.w);
                av[4] = (short)f2bf(u1.x); av[5] = (short)f2bf(u1.y);
                av[6] = (short)f2bf(u1.z); av[7] = (short)f2bf(u1.w);
                a[mt] = av;
            }
        }
        #pragma unroll
        for (int n = 0; n < 8; n++) {
            s8v b = *(const s8v*)(Wt + (size_t)(n * 16 + m) * D + k0);
            acc[0][n] = __builtin_amdgcn_mfma_f32_16x16x32_bf16(a[0], b, acc[0][n], 0, 0, 0);
            acc[1][n] = __builtin_amdgcn_mfma_f32_16x16x32_bf16(a[1], b, acc[1][n], 0, 0, 0);
        }
    }
    float disv[2][4];
    #pragma unroll
    for (int mt = 0; mt < 2; mt++)
        #pragma unroll
        for (int r = 0; r < 4; r++) {
            int row = rbase + mt * 16 + q * 4 + r;
            if (row >= N_NODES) row = N_NODES - 1;
            disv[mt][r] = dis[row];
        }
    #pragma unroll
    for (int mt = 0; mt < 2; mt++)
        #pragma unroll
        for (int n = 0; n < 8; n++)
            #pragma unroll
            for (int r = 0; r < 4; r++) {
                int row = wv * 32 + mt * 16 + q * 4 + r;
                Cs[row * 136 + n * 16 + m] = f2bf(acc[mt][n][r] * disv[mt][r]);
            }
    __syncthreads();
    int gbase = blockIdx.x * 128;
    #pragma unroll
    for (int it = 0; it < 8; it++) {
        int cid = t + it * 256;
        int row = cid >> 4, off = (cid & 15) * 8;
        int grow = gbase + row;
        if (grow < N_NODES) {
            s8v v = *(const s8v*)(Cs + row * 136 + off);
            *(s8v*)(Hb + (size_t)grow * D + off) = v;
        }
    }
}

// ---- aggregate: out = relu(dis[n]*(Hb[n]+sum Hb[src])+b), 16 lanes/node ----
// R8 form: unconditional 8-wide unroll, scalar index loads (L1-hot), max gather ILP.
__device__ __forceinline__ void acc8(float* a, uint4 v) {
    a[0] += bf_lo(v.x); a[1] += bf_hi(v.x);
    a[2] += bf_lo(v.y); a[3] += bf_hi(v.y);
    a[4] += bf_lo(v.z); a[5] += bf_hi(v.z);
    a[6] += bf_lo(v.w); a[7] += bf_hi(v.w);
}

template<bool BF16OUT>
__global__ __launch_bounds__(256) void aggr_kernel(const uint4* __restrict__ Hb4,
                                                   const float* __restrict__ dis,
                                                   const int* __restrict__ rowstart,
                                                   const ushort* __restrict__ e16,
                                                   const float* __restrict__ bias,
                                                   void* __restrict__ Hout) {
    int t = threadIdx.x;
    int li = t & 15;                       // lane in group: channels li*8..li*8+7
    int n = blockIdx.x * 16 + (t >> 4);    // 50000 = 3125*16
    float dn = dis[n];
    float a[8];
    {
        uint4 sv = Hb4[(size_t)n * 16 + li];   // self term (dis[n] folded into Hb)
        a[0] = bf_lo(sv.x); a[1] = bf_hi(sv.x);
        a[2] = bf_lo(sv.y); a[3] = bf_hi(sv.y);
        a[4] = bf_lo(sv.z); a[5] = bf_hi(sv.z);
        a[6] = bf_lo(sv.w); a[7] = bf_hi(sv.w);
    }
    int beg = rowstart[n], end = rowstart[n + 1];
    int p = beg;
    for (; p + 7 < end; p += 8) {          // 8 outstanding 16B gathers per lane
        int s[8];
        #pragma unroll
        for (int j = 0; j < 8; j++) s[j] = e16[p + j];
        uint4 v[8];
        #pragma unroll
        for (int j = 0; j < 8; j++) v[j] = Hb4[(size_t)s[j] * 16 + li];
        #pragma unroll
        for (int j = 0; j < 8; j++) acc8(a, v[j]);
    }
    for (; p + 3 < end; p += 4) {
        int s0 = e16[p + 0], s1 = e16[p + 1], s2 = e16[p + 2], s3 = e16[p + 3];
        uint4 v0 = Hb4[(size_t)s0 * 16 + li];
        uint4 v1 = Hb4[(size_t)s1 * 16 + li];
        uint4 v2 = Hb4[(size_t)s2 * 16 + li];
        uint4 v3 = Hb4[(size_t)s3 * 16 + li];
        acc8(a, v0); acc8(a, v1); acc8(a, v2); acc8(a, v3);
    }
    for (; p < end; p++) {
        uint4 v0 = Hb4[(size_t)e16[p] * 16 + li];
        acc8(a, v0);
    }
    const float4* b4 = (const float4*)bias;
    float4 bb0 = b4[li * 2], bb1 = b4[li * 2 + 1];
    float r0 = fmaxf(fmaf(dn, a[0], bb0.x), 0.f);
    float r1 = fmaxf(fmaf(dn, a[1], bb0.y), 0.f);
    float r2 = fmaxf(fmaf(dn, a[2], bb0.z), 0.f);
    float r3 = fmaxf(fmaf(dn, a[3], bb0.w), 0.f);
    float r4 = fmaxf(fmaf(dn, a[4], bb1.x), 0.f);
    float r5 = fmaxf(fmaf(dn, a[5], bb1.y), 0.f);
    float r6 = fmaxf(fmaf(dn, a[6], bb1.z), 0.f);
    float r7 = fmaxf(fmaf(dn, a[7], bb1.w), 0.f);
    if (BF16OUT) {
        uint4 o;
        o.x = (uint32)f2bf(r0) | ((uint32)f2bf(r1) << 16);
        o.y = (uint32)f2bf(r2) | ((uint32)f2bf(r3) << 16);
        o.z = (uint32)f2bf(r4) | ((uint32)f2bf(r5) << 16);
        o.w = (uint32)f2bf(r6) | ((uint32)f2bf(r7) << 16);
        ((uint4*)Hout)[(size_t)n * 16 + li] = o;
    } else {
        float4* H4 = (float4*)Hout;
        float4 o0; o0.x = r0; o0.y = r1; o0.z = r2; o0.w = r3;
        float4 o1; o1.x = r4; o1.y = r5; o1.z = r6; o1.w = r7;
        H4[(size_t)n * 32 + li * 2]     = o0;
        H4[(size_t)n * 32 + li * 2 + 1] = o1;
    }
}

extern "C" void kernel_launch(void* const* d_in, const int* in_sizes, int n_in,
                              void* d_out, int out_size, void* d_ws, size_t ws_size,
                              hipStream_t stream) {
    const float* x  = (const float*)d_in[0];
    const int*   ei = (const int*)d_in[1];   // int32 per harness contract
    const float* W1 = (const float*)d_in[2];
    const float* b1 = (const float*)d_in[3];
    const float* W2 = (const float*)d_in[4];
    const float* b2 = (const float*)d_in[5];
    float* out = (float*)d_out;

    char* ws = (char*)d_ws;
    size_t off = 0;
    auto alloc = [&](size_t bytes) -> void* {
        void* p = ws + off;
        off += (bytes + 255) & ~(size_t)255;
        return p;
    };
    int*    histM    = (int*)alloc((size_t)LHM * 4);
    int*    base     = (int*)alloc((size_t)LHM * 4);
    int*    bsum     = (int*)alloc((size_t)NSB * 4);
    int*    rowstart = (int*)alloc((size_t)(N_NODES + 1) * 4);
    float*  dis      = (float*)alloc((size_t)N_NODES * 4);
    uint32* edgeTmp  = (uint32*)alloc((size_t)N_EDGES * 4);
    ushort* e16      = (ushort*)alloc((size_t)N_EDGES * 2);
    ushort* Hb       = (ushort*)alloc((size_t)N_NODES * D * 2);
    ushort* HO1      = (ushort*)alloc((size_t)N_NODES * D * 2);   // layer-1 out bf16
    ushort* W1t      = (ushort*)alloc((size_t)D * D * 2);
    ushort* W2t      = (ushort*)alloc((size_t)D * D * 2);

    const int* src = ei;             // edge_index[0]
    const int* dst = ei + N_EDGES;   // edge_index[1]

    phaseA_kernel<<<NB + 2, 256, 0, stream>>>(dst, histM, W1, W2, W1t, W2t);
    scan1g<<<NSB, 256, 0, stream>>>(histM, base, bsum);
    scan23g<<<NSB, 256, 0, stream>>>(base, bsum);
    phaseC_kernel<<<NB, 256, 0, stream>>>(src, dst, base, edgeTmp);
    phaseD_kernel<<<NBKT, 256, 0, stream>>>(edgeTmp, base, rowstart, dis, e16);

    gemm_mfma<false><<<GB, 256, 0, stream>>>(x, W1t, dis, Hb);
    aggr_kernel<true><<<N_NODES / 16, 256, 0, stream>>>((const uint4*)Hb, dis, rowstart,
                                                        e16, b1, HO1);
    gemm_mfma<true><<<GB, 256, 0, stream>>>(HO1, W2t, dis, Hb);
    aggr_kernel<false><<<N_NODES / 16, 256, 0, stream>>>((const uint4*)Hb, dis, rowstart,
                                                         e16, b2, out);
}